// Round 1
// baseline (24740.854 us; speedup 1.0000x reference)
//
#include <hip/hip_runtime.h>

#define TT 32768
#define BB 32
#define HH 64

__device__ __forceinline__ float sigm(float v) { return 1.f / (1.f + __expf(-v)); }
__device__ __forceinline__ float tanh_fast(float v) {
    float e = __expf(2.f * v);
    return 1.f - 2.f / (e + 1.f);   // saturates correctly for |v| large (inf-safe)
}

// Reduce one 64-step window of per-lane output partials and store 64 outputs.
// Called by wave 0 only; prow = pbuf[parity] (rows padded to 65 -> conflict-free).
__device__ __forceinline__ void flush_window(
    const float (*__restrict__ prow)[65], int t0, int b, int l,
    const float* __restrict__ x, float bo, float* __restrict__ out)
{
    float s0 = 0.f, s1 = 0.f, s2 = 0.f, s3 = 0.f;
    #pragma unroll
    for (int j = 0; j < 16; ++j) {
        s0 += prow[l][4 * j + 0];
        s1 += prow[l][4 * j + 1];
        s2 += prow[l][4 * j + 2];
        s3 += prow[l][4 * j + 3];
    }
    const float s = (s0 + s1) + (s2 + s3);
    const int tt = t0 + l;
    out[(size_t)tt * BB + b] = s + bo + x[tt * BB + b];
}

__global__ __launch_bounds__(256, 1) void lstm_fused(
    const float* __restrict__ x,      // [T,B]
    const float* __restrict__ W_ih,   // [256]
    const float* __restrict__ W_hh,   // [256,64]
    const float* __restrict__ b_ih,   // [256]
    const float* __restrict__ b_hh,   // [256]
    const float* __restrict__ W_out,  // [64]
    const float* __restrict__ b_out,  // [1]
    float* __restrict__ out)          // [T,B]
{
    const int b   = blockIdx.x;       // batch element
    const int tid = threadIdx.x;
    const int w   = tid >> 6;         // wave = gate type (0=i,1=f,2=g,3=o)
    const int l   = tid & 63;         // lane = h index

    __shared__ float gbuf[2][4][64];  // gate exchange, double-buffered by t&1
    __shared__ float hbuf[4][64];     // per-wave private h broadcast buffer
    __shared__ float pbuf[2][64][65]; // output partials ring: [window parity][step][lane], padded

    // W_hh row for this thread's gate, stationary in registers (64 VGPRs).
    float wr[64];
    #pragma unroll
    for (int k = 0; k < 16; ++k) {
        const float4 v = *reinterpret_cast<const float4*>(&W_hh[tid * 64 + k * 4]);
        wr[4 * k + 0] = v.x; wr[4 * k + 1] = v.y;
        wr[4 * k + 2] = v.z; wr[4 * k + 3] = v.w;
    }
    const float wih  = W_ih[tid];
    const float bias = b_ih[tid] + b_hh[tid];
    const float wo_l = W_out[l];
    const float bo   = b_out[0];

    float c = 0.f;
    hbuf[w][l] = 0.f;                 // h0 = 0 (each wave inits its own copy)
    __syncthreads();

    // x broadcast prefetch, 2 steps deep
    float xv0 = x[b];
    float xv1 = x[BB + b];

    for (int t = 0; t < TT; ++t) {
        // Periodic output flush: wave 0 reduces the previous 64-step window
        // while waves 1..3 run ahead into this step's dot product.
        if ((t & 63) == 0 && t > 0) {
            __syncthreads();          // make wave-3 pbuf writes visible
            if (w == 0) {
                const int fp = ((t >> 6) & 1) ^ 1;
                flush_window(pbuf[fp], t - 64, b, l, x, bo, out);
            }
        }

        const float xv = xv0; xv0 = xv1;
        int tn = t + 2; if (tn > TT - 1) tn = TT - 1;
        xv1 = x[tn * BB + b];

        // gates_pre[r] = sum_k W_hh[r,k] * h[k]  (h broadcast from own-wave LDS copy)
        float a0 = 0.f, a1 = 0.f, a2 = 0.f, a3 = 0.f;
        #pragma unroll
        for (int k = 0; k < 16; ++k) {
            const float4 hv = *reinterpret_cast<const float4*>(&hbuf[w][k * 4]);
            a0 = fmaf(wr[4 * k + 0], hv.x, a0);
            a1 = fmaf(wr[4 * k + 1], hv.y, a1);
            a2 = fmaf(wr[4 * k + 2], hv.z, a2);
            a3 = fmaf(wr[4 * k + 3], hv.w, a3);
        }
        const float pre = (a0 + a1) + (a2 + a3) + xv * wih + bias;
        const float gv  = (w == 2) ? tanh_fast(pre) : sigm(pre);

        const int p = t & 1;
        gbuf[p][w][l] = gv;
        __syncthreads();

        // every wave redundantly computes c,h for its lane (bit-identical across waves)
        const float iv = gbuf[p][0][l];
        const float fv = gbuf[p][1][l];
        const float gg = gbuf[p][2][l];
        const float ov = gbuf[p][3][l];
        c = fmaf(fv, c, iv * gg);
        const float hn = ov * tanh_fast(c);
        hbuf[w][l] = hn;              // own-wave broadcast copy for next step (wave-synchronous)
        if (w == 3) pbuf[(t >> 6) & 1][t & 63][l] = hn * wo_l;  // output partial
    }

    // Final window (steps TT-64 .. TT-1)
    __syncthreads();
    if (w == 0) {
        flush_window(pbuf[((TT >> 6) & 1) ^ 1], TT - 64, b, l, x, bo, out);
    }
}

extern "C" void kernel_launch(void* const* d_in, const int* in_sizes, int n_in,
                              void* d_out, int out_size, void* d_ws, size_t ws_size,
                              hipStream_t stream) {
    (void)in_sizes; (void)n_in; (void)d_ws; (void)ws_size; (void)out_size;
    const float* x    = (const float*)d_in[0];
    const float* wih  = (const float*)d_in[1];
    const float* whh  = (const float*)d_in[2];
    const float* bih  = (const float*)d_in[3];
    const float* bhh  = (const float*)d_in[4];
    const float* wout = (const float*)d_in[5];
    const float* bout = (const float*)d_in[6];
    hipLaunchKernelGGL(lstm_fused, dim3(BB), dim3(256), 0, stream,
                       x, wih, whh, bih, bhh, wout, bout, (float*)d_out);
}

// Round 2
// 18621.768 us; speedup vs baseline: 1.3286x; 1.3286x over previous
//
#include <hip/hip_runtime.h>

#define TT 32768
#define BB 32

__device__ __forceinline__ float sigm(float v) { return 1.f / (1.f + __expf(-v)); }
__device__ __forceinline__ float tanh_fast(float v) {
    float e = __expf(2.f * v);
    return 1.f - 2.f / (e + 1.f);   // saturates correctly for large |v|
}

// Reduce one 64-step window of per-lane output partials and store 64 outputs.
// prow[step][lane] (rows padded to 65 -> conflict-free); xrow[step] = stashed x.
__device__ __forceinline__ void flush_window(
    const float (*__restrict__ prow)[65], const float* __restrict__ xrow,
    int t0, int b, int l, float bo, float* __restrict__ out)
{
    float s0 = 0.f, s1 = 0.f, s2 = 0.f, s3 = 0.f;
    #pragma unroll
    for (int j = 0; j < 16; ++j) {
        s0 += prow[l][4 * j + 0];
        s1 += prow[l][4 * j + 1];
        s2 += prow[l][4 * j + 2];
        s3 += prow[l][4 * j + 3];
    }
    out[(size_t)(t0 + l) * BB + b] = (s0 + s1) + (s2 + s3) + bo + xrow[l];
}

__global__ __launch_bounds__(256, 1) void lstm_fused(
    const float* __restrict__ x,      // [T,B]
    const float* __restrict__ W_ih,   // [256]
    const float* __restrict__ W_hh,   // [256,64]
    const float* __restrict__ b_ih,   // [256]
    const float* __restrict__ b_hh,   // [256]
    const float* __restrict__ W_out,  // [64]
    const float* __restrict__ b_out,  // [1]
    float* __restrict__ out)          // [T,B]
{
    const int b   = blockIdx.x;       // batch element
    const int tid = threadIdx.x;
    const int w   = tid >> 6;         // wave = gate type (0=i,1=f,2=g,3=o)
    const int l   = tid & 63;         // lane = h index

    __shared__ float gbuf[2][4][64];  // gate exchange, double-buffered by t&1
    __shared__ float pbuf[2][64][65]; // output partials ring [win parity][step][lane]
    __shared__ float xbuf[2][64];     // stashed x per window (for flush)

    // W_hh row for this thread's gate — load, then PIN in VGPRs (the asm result
    // cannot be rematerialized as a load; round-1 compiler demoted this array).
    float wr[64];
    #pragma unroll
    for (int k = 0; k < 16; ++k) {
        const float4 v = *reinterpret_cast<const float4*>(&W_hh[tid * 64 + k * 4]);
        wr[4 * k + 0] = v.x; wr[4 * k + 1] = v.y;
        wr[4 * k + 2] = v.z; wr[4 * k + 3] = v.w;
    }
    #pragma unroll
    for (int k = 0; k < 64; ++k) asm volatile("" : "+v"(wr[k]));

    const float wih  = W_ih[tid];
    const float bias = b_ih[tid] + b_hh[tid];
    const float wo_l = W_out[l];
    const float bo   = b_out[0];

    float c  = 0.f;
    float hn = 0.f;                   // h_{t-1}[l], identical across waves

    // x broadcast prefetch, 2 steps deep (uniform address per block -> 1 line)
    float xv0 = x[b];
    float xv1 = x[BB + b];

    for (int t = 0; t < TT; ++t) {
        const float xv = xv0; xv0 = xv1;
        int tn = t + 2; if (tn > TT - 1) tn = TT - 1;
        xv1 = x[tn * BB + b];

        // stash x for the flush (one lane of wave 0)
        if (w == 0 && l == (t & 63)) xbuf[(t >> 6) & 1][t & 63] = xv;

        // gates_pre[r] = xg + sum_k W_hh[r,k]*h[k]; h broadcast via v_readlane
        float a0 = fmaf(xv, wih, bias), a1 = 0.f, a2 = 0.f, a3 = 0.f;
        const unsigned hb = __float_as_uint(hn);
        #pragma unroll
        for (int k = 0; k < 16; ++k) {
            const float h0 = __uint_as_float(__builtin_amdgcn_readlane(hb, 4 * k + 0));
            const float h1 = __uint_as_float(__builtin_amdgcn_readlane(hb, 4 * k + 1));
            const float h2 = __uint_as_float(__builtin_amdgcn_readlane(hb, 4 * k + 2));
            const float h3 = __uint_as_float(__builtin_amdgcn_readlane(hb, 4 * k + 3));
            a0 = fmaf(wr[4 * k + 0], h0, a0);
            a1 = fmaf(wr[4 * k + 1], h1, a1);
            a2 = fmaf(wr[4 * k + 2], h2, a2);
            a3 = fmaf(wr[4 * k + 3], h3, a3);
        }
        const float pre = (a0 + a1) + (a2 + a3);
        const float gv  = (w == 2) ? tanh_fast(pre) : sigm(pre);

        const int p = t & 1;
        gbuf[p][w][l] = gv;
        __syncthreads();

        // Periodic flush AFTER the step barrier: wave-3's pbuf writes for the
        // previous window (its last write precedes its arrival here) are visible.
        // Wave 0 reduces while waves 1-3 run ahead (they block at barrier t+1).
        if ((t & 63) == 0 && t > 0 && w == 0) {
            const int fp = ((t >> 6) & 1) ^ 1;
            flush_window(pbuf[fp], xbuf[fp], t - 64, b, l, bo, out);
        }

        // every wave redundantly computes c,h (bit-identical across waves)
        const float iv = gbuf[p][0][l];
        const float fv = gbuf[p][1][l];
        const float gg = gbuf[p][2][l];
        const float ov = gbuf[p][3][l];
        c  = fmaf(fv, c, iv * gg);
        hn = ov * tanh_fast(c);
        if (w == 3) pbuf[(t >> 6) & 1][t & 63][l] = hn * wo_l;  // output partial
    }

    // Final window (steps TT-64 .. TT-1)
    __syncthreads();
    if (w == 0) {
        const int fp = ((TT >> 6) & 1) ^ 1;
        flush_window(pbuf[fp], xbuf[fp], TT - 64, b, l, bo, out);
    }
}

extern "C" void kernel_launch(void* const* d_in, const int* in_sizes, int n_in,
                              void* d_out, int out_size, void* d_ws, size_t ws_size,
                              hipStream_t stream) {
    (void)in_sizes; (void)n_in; (void)d_ws; (void)ws_size; (void)out_size;
    const float* x    = (const float*)d_in[0];
    const float* wih  = (const float*)d_in[1];
    const float* whh  = (const float*)d_in[2];
    const float* bih  = (const float*)d_in[3];
    const float* bhh  = (const float*)d_in[4];
    const float* wout = (const float*)d_in[5];
    const float* bout = (const float*)d_in[6];
    hipLaunchKernelGGL(lstm_fused, dim3(BB), dim3(256), 0, stream,
                       x, wih, whh, bih, bhh, wout, bout, (float*)d_out);
}

// Round 4
// 18008.545 us; speedup vs baseline: 1.3738x; 1.0341x over previous
//
#include <hip/hip_runtime.h>

#define TT 32768
#define BB 32

typedef _Float16 half2_t __attribute__((ext_vector_type(2)));
typedef __fp16   fp16v2  __attribute__((ext_vector_type(2)));

union H2U { half2_t h2; fp16v2 p; unsigned u; _Float16 h[2]; };

__device__ __forceinline__ unsigned packh2(float a, float b) {
    H2U t; t.h[0] = (_Float16)a; t.h[1] = (_Float16)b; return t.u;
}

__device__ __forceinline__ float fdot2u(unsigned wu, unsigned hu, float acc) {
    H2U w, h; w.u = wu; h.u = hu;
    return __builtin_amdgcn_fdot2(w.h2, h.h2, acc, false);
}

__device__ __forceinline__ float sigm(float v) {
    return __builtin_amdgcn_rcpf(1.f + __expf(-v));
}
__device__ __forceinline__ float tanh_fast(float v) {
    float e = __expf(2.f * v);
    return 1.f - 2.f * __builtin_amdgcn_rcpf(e + 1.f);  // saturates for large |v|
}

// One wave (64 threads) per batch element. Lane l owns h-index l and computes
// gates i,f,g,o[l] each step. Everything in-register; no __syncthreads in the
// main loop. Weights: 4x32 packed fp16 pairs = 128 VGPRs, constant-indexed.
__global__ __launch_bounds__(64, 1) void lstm_fused(
    const float* __restrict__ x,      // [T,B]
    const float* __restrict__ W_ih,   // [256]
    const float* __restrict__ W_hh,   // [256,64]  rows: i,f,g,o
    const float* __restrict__ b_ih,   // [256]
    const float* __restrict__ b_hh,   // [256]
    const float* __restrict__ W_out,  // [64]
    const float* __restrict__ b_out,  // [1]
    float* __restrict__ out)          // [T,B]
{
    const int b = blockIdx.x;
    const int l = threadIdx.x & 63;

    __shared__ float pbuf[64][65];    // [step-in-window][lane] output partials

    // Pack W_hh rows for this lane's 4 gates into fp16 pairs (startup only).
    unsigned wi[32], wf[32], wg[32], wo_[32];
    #pragma unroll
    for (int j = 0; j < 16; ++j) {
        const float4 vi = *reinterpret_cast<const float4*>(&W_hh[(0 * 64 + l) * 64 + 4 * j]);
        const float4 vf = *reinterpret_cast<const float4*>(&W_hh[(1 * 64 + l) * 64 + 4 * j]);
        const float4 vg = *reinterpret_cast<const float4*>(&W_hh[(2 * 64 + l) * 64 + 4 * j]);
        const float4 vo = *reinterpret_cast<const float4*>(&W_hh[(3 * 64 + l) * 64 + 4 * j]);
        wi[2 * j] = packh2(vi.x, vi.y);  wi[2 * j + 1] = packh2(vi.z, vi.w);
        wf[2 * j] = packh2(vf.x, vf.y);  wf[2 * j + 1] = packh2(vf.z, vf.w);
        wg[2 * j] = packh2(vg.x, vg.y);  wg[2 * j + 1] = packh2(vg.z, vg.w);
        wo_[2 * j] = packh2(vo.x, vo.y); wo_[2 * j + 1] = packh2(vo.z, vo.w);
    }

    const float wih_i = W_ih[l],       bia_i = b_ih[l]       + b_hh[l];
    const float wih_f = W_ih[64 + l],  bia_f = b_ih[64 + l]  + b_hh[64 + l];
    const float wih_g = W_ih[128 + l], bia_g = b_ih[128 + l] + b_hh[128 + l];
    const float wih_o = W_ih[192 + l], bia_o = b_ih[192 + l] + b_hh[192 + l];
    const float wo_l  = W_out[l];
    const float bo    = b_out[0];

    float c = 0.f, hn = 0.f;
    unsigned hpk = 0;                 // packed (h[2j],h[2j+1]) — valid on even lanes

    // uniform-address x prefetch, 2 steps deep
    float xv0 = x[b];
    float xv1 = x[BB + b];

    #pragma unroll 1
    for (int t = 0; t < TT; ++t) {
        const float xv = xv0; xv0 = xv1;
        int tn = t + 2; if (tn > TT - 1) tn = TT - 1;
        xv1 = x[tn * BB + b];

        float ai = fmaf(xv, wih_i, bia_i);
        float af = fmaf(xv, wih_f, bia_f);
        float ag = fmaf(xv, wih_g, bia_g);
        float ao = fmaf(xv, wih_o, bia_o);
        #pragma unroll
        for (int j = 0; j < 32; ++j) {
            const unsigned hp = (unsigned)__builtin_amdgcn_readlane((int)hpk, 2 * j);
            ai = fdot2u(wi[j],  hp, ai);
            af = fdot2u(wf[j],  hp, af);
            ag = fdot2u(wg[j],  hp, ag);
            ao = fdot2u(wo_[j], hp, ao);
        }
        const float iv = sigm(ai);
        const float fv = sigm(af);
        const float gg = tanh_fast(ag);
        const float ov = sigm(ao);
        c  = fmaf(fv, c, iv * gg);
        hn = ov * tanh_fast(c);

        // repack h for next step's broadcast: even lane 2j gets (h[2j],h[2j+1])
        const float hb = __shfl_xor(hn, 1, 64);
        H2U hh; hh.p = __builtin_amdgcn_cvt_pkrtz(hn, hb);
        hpk = hh.u;

        pbuf[t & 63][l] = hn * wo_l;  // output partial (stride-1, conflict-free)

        if ((t & 63) == 63) {
            __syncthreads();          // 1-wave barrier: just orders LDS (cheap)
            // lane l reduces row l -> output for step t0+l
            float s0 = 0.f, s1 = 0.f, s2 = 0.f, s3 = 0.f;
            #pragma unroll
            for (int j2 = 0; j2 < 16; ++j2) {
                const float4 v = *reinterpret_cast<const float4*>(&pbuf[l][4 * j2]);
                s0 += v.x; s1 += v.y; s2 += v.z; s3 += v.w;
            }
            const int tt = (t & ~63) + l;
            out[(size_t)tt * BB + b] = (s0 + s1) + (s2 + s3) + bo + x[(size_t)tt * BB + b];
        }
    }
}

extern "C" void kernel_launch(void* const* d_in, const int* in_sizes, int n_in,
                              void* d_out, int out_size, void* d_ws, size_t ws_size,
                              hipStream_t stream) {
    (void)in_sizes; (void)n_in; (void)d_ws; (void)ws_size; (void)out_size;
    const float* x    = (const float*)d_in[0];
    const float* wih  = (const float*)d_in[1];
    const float* whh  = (const float*)d_in[2];
    const float* bih  = (const float*)d_in[3];
    const float* bhh  = (const float*)d_in[4];
    const float* wout = (const float*)d_in[5];
    const float* bout = (const float*)d_in[6];
    hipLaunchKernelGGL(lstm_fused, dim3(BB), dim3(64), 0, stream,
                       x, wih, whh, bih, bhh, wout, bout, (float*)d_out);
}

// Round 5
// 17246.243 us; speedup vs baseline: 1.4346x; 1.0442x over previous
//
#include <hip/hip_runtime.h>

#define TT 32768
#define BB 32

typedef _Float16 half2_t __attribute__((ext_vector_type(2)));
typedef __fp16   fp16v2  __attribute__((ext_vector_type(2)));

union H2U { half2_t h2; fp16v2 p; unsigned u; _Float16 h[2]; };

__device__ __forceinline__ unsigned packh2(float a, float b) {
    H2U t; t.h[0] = (_Float16)a; t.h[1] = (_Float16)b; return t.u;
}

__device__ __forceinline__ float fdot2u(unsigned wu, unsigned hu, float acc) {
    H2U w, h; w.u = wu; h.u = hu;
    return __builtin_amdgcn_fdot2(w.h2, h.h2, acc, false);
}

__device__ __forceinline__ float sigm(float v) {
    return __builtin_amdgcn_rcpf(1.f + __expf(-v));
}
__device__ __forceinline__ float tanh_fast(float v) {
    float e = __expf(2.f * v);
    return 1.f - 2.f * __builtin_amdgcn_rcpf(e + 1.f);  // saturates for large |v|
}

// One wave (64 threads) per batch element. Lane l owns h-index l and computes
// gates i,f,g,o[l] each step. No LDS in the recurrence. Weights: 4x32 packed
// fp16 pairs = 128 VGPRs. amdgpu_waves_per_eu(1,1) lifts the allocator's
// occupancy-driven VGPR cap (rounds 1/2/4 all demoted the weight file).
__global__ __attribute__((amdgpu_waves_per_eu(1, 1))) __launch_bounds__(64)
void lstm_fused(
    const float* __restrict__ x,      // [T,B]
    const float* __restrict__ W_ih,   // [256]
    const float* __restrict__ W_hh,   // [256,64]  rows: i,f,g,o
    const float* __restrict__ b_ih,   // [256]
    const float* __restrict__ b_hh,   // [256]
    const float* __restrict__ W_out,  // [64]
    const float* __restrict__ b_out,  // [1]
    float* __restrict__ out)          // [T,B]
{
    const int b = blockIdx.x;
    const int l = threadIdx.x & 63;

    __shared__ float pbuf[64][65];    // [step-in-window][lane] output partials

    // Pack W_hh rows for this lane's 4 gates into fp16 pairs (startup only).
    unsigned wi[32], wf[32], wg[32], wo_[32];
    #pragma unroll
    for (int j = 0; j < 16; ++j) {
        const float4 vi = *reinterpret_cast<const float4*>(&W_hh[(0 * 64 + l) * 64 + 4 * j]);
        const float4 vf = *reinterpret_cast<const float4*>(&W_hh[(1 * 64 + l) * 64 + 4 * j]);
        const float4 vg = *reinterpret_cast<const float4*>(&W_hh[(2 * 64 + l) * 64 + 4 * j]);
        const float4 vo = *reinterpret_cast<const float4*>(&W_hh[(3 * 64 + l) * 64 + 4 * j]);
        wi[2 * j] = packh2(vi.x, vi.y);  wi[2 * j + 1] = packh2(vi.z, vi.w);
        wf[2 * j] = packh2(vf.x, vf.y);  wf[2 * j + 1] = packh2(vf.z, vf.w);
        wg[2 * j] = packh2(vg.x, vg.y);  wg[2 * j + 1] = packh2(vg.z, vg.w);
        wo_[2 * j] = packh2(vo.x, vo.y); wo_[2 * j + 1] = packh2(vo.z, vo.w);
    }

    const float wih_i = W_ih[l],       bia_i = b_ih[l]       + b_hh[l];
    const float wih_f = W_ih[64 + l],  bia_f = b_ih[64 + l]  + b_hh[64 + l];
    const float wih_g = W_ih[128 + l], bia_g = b_ih[128 + l] + b_hh[128 + l];
    const float wih_o = W_ih[192 + l], bia_o = b_ih[192 + l] + b_hh[192 + l];
    const float wo_l  = W_out[l];
    const float bo    = b_out[0];

    float c = 0.f, hn = 0.f;
    unsigned hpk = 0;                 // packed (h[2j],h[2j+1]) — valid on even lanes

    // uniform-address x prefetch, 2 steps deep
    float xv0 = x[b];
    float xv1 = x[BB + b];

    #pragma unroll 1
    for (int t = 0; t < TT; ++t) {
        const float xv = xv0; xv0 = xv1;
        int tn = t + 2; if (tn > TT - 1) tn = TT - 1;
        xv1 = x[tn * BB + b];

        float ai = fmaf(xv, wih_i, bia_i);
        float af = fmaf(xv, wih_f, bia_f);
        float ag = fmaf(xv, wih_g, bia_g);
        float ao = fmaf(xv, wih_o, bia_o);
        #pragma unroll
        for (int j = 0; j < 32; ++j) {
            const unsigned hp = (unsigned)__builtin_amdgcn_readlane((int)hpk, 2 * j);
            ai = fdot2u(wi[j],  hp, ai);
            af = fdot2u(wf[j],  hp, af);
            ag = fdot2u(wg[j],  hp, ag);
            ao = fdot2u(wo_[j], hp, ao);
        }
        const float iv = sigm(ai);
        const float fv = sigm(af);
        const float gg = tanh_fast(ag);
        const float ov = sigm(ao);
        c  = fmaf(fv, c, iv * gg);
        hn = ov * tanh_fast(c);

        // repack h for next step's broadcast: even lane 2j gets (h[2j],h[2j+1]).
        // neighbor swap via DPP quad_perm [1,0,3,2] — single VALU op, no LDS.
        const float hb = __uint_as_float((unsigned)__builtin_amdgcn_mov_dpp(
            (int)__float_as_uint(hn), 0xB1, 0xF, 0xF, true));
        H2U hh; hh.p = __builtin_amdgcn_cvt_pkrtz(hn, hb);
        hpk = hh.u;

        pbuf[t & 63][l] = hn * wo_l;  // output partial (stride-1, conflict-free)

        if ((t & 63) == 63) {
            __syncthreads();          // 1-wave barrier: just orders LDS (cheap)
            // lane l reduces row l -> output for step t0+l
            float s0 = 0.f, s1 = 0.f, s2 = 0.f, s3 = 0.f;
            #pragma unroll
            for (int j2 = 0; j2 < 16; ++j2) {
                const float4 v = *reinterpret_cast<const float4*>(&pbuf[l][4 * j2]);
                s0 += v.x; s1 += v.y; s2 += v.z; s3 += v.w;
            }
            const int tt = (t & ~63) + l;
            out[(size_t)tt * BB + b] = (s0 + s1) + (s2 + s3) + bo + x[(size_t)tt * BB + b];
        }
    }
}

extern "C" void kernel_launch(void* const* d_in, const int* in_sizes, int n_in,
                              void* d_out, int out_size, void* d_ws, size_t ws_size,
                              hipStream_t stream) {
    (void)in_sizes; (void)n_in; (void)d_ws; (void)ws_size; (void)out_size;
    const float* x    = (const float*)d_in[0];
    const float* wih  = (const float*)d_in[1];
    const float* whh  = (const float*)d_in[2];
    const float* bih  = (const float*)d_in[3];
    const float* bhh  = (const float*)d_in[4];
    const float* wout = (const float*)d_in[5];
    const float* bout = (const float*)d_in[6];
    hipLaunchKernelGGL(lstm_fused, dim3(BB), dim3(64), 0, stream,
                       x, wih, whh, bih, bhh, wout, bout, (float*)d_out);
}

// Round 6
// 14243.742 us; speedup vs baseline: 1.7370x; 1.2108x over previous
//
#include <hip/hip_runtime.h>

#define TT 32768
#define BB 32

typedef _Float16 half2_t __attribute__((ext_vector_type(2)));
typedef __fp16   fp16v2  __attribute__((ext_vector_type(2)));

union H2U { half2_t h2; fp16v2 p; unsigned u; _Float16 h[2]; };

__device__ __forceinline__ unsigned packh2(float a, float b) {
    H2U t; t.h[0] = (_Float16)a; t.h[1] = (_Float16)b; return t.u;
}

__device__ __forceinline__ float fdot2u(unsigned wu, unsigned hu, float acc) {
    H2U w, h; w.u = wu; h.u = hu;
    return __builtin_amdgcn_fdot2(w.h2, h.h2, acc, false);
}

__device__ __forceinline__ float rlanef(float v, int lane) {
    return __uint_as_float((unsigned)__builtin_amdgcn_readlane((int)__float_as_uint(v), lane));
}

__device__ __forceinline__ float sigm(float v) {
    return __builtin_amdgcn_rcpf(1.f + __expf(-v));
}
__device__ __forceinline__ float tanh_fast(float v) {
    float e = __expf(2.f * v);
    return 1.f - 2.f * __builtin_amdgcn_rcpf(e + 1.f);  // saturates for large |v|
}

// One wave (64 threads) per batch element. Lane l owns h-index l, computes all
// 4 gates. ZERO global/buffer ops in the recurrence: x comes from a per-window
// register (xwin, lane s = x[t0+s]) via v_readlane with uniform dynamic index;
// h broadcast via v_readlane of packed fp16 pairs; weights (128 packed words)
// pinned by amdgpu_waves_per_eu(1,1)'s 512-VGPR budget.
__global__ __attribute__((amdgpu_waves_per_eu(1, 1))) __launch_bounds__(64)
void lstm_fused(
    const float* __restrict__ x,      // [T,B]
    const float* __restrict__ W_ih,   // [256]
    const float* __restrict__ W_hh,   // [256,64]  rows: i,f,g,o
    const float* __restrict__ b_ih,   // [256]
    const float* __restrict__ b_hh,   // [256]
    const float* __restrict__ W_out,  // [64]
    const float* __restrict__ b_out,  // [1]
    float* __restrict__ out)          // [T,B]
{
    const int b = blockIdx.x;
    const int l = threadIdx.x & 63;

    __shared__ float pbuf[64][65];    // [step-in-window][lane] output partials

    // Pack W_hh rows for this lane's 4 gates into fp16 pairs (startup only).
    unsigned wi[32], wf[32], wg[32], wo_[32];
    #pragma unroll
    for (int j = 0; j < 16; ++j) {
        const float4 vi = *reinterpret_cast<const float4*>(&W_hh[(0 * 64 + l) * 64 + 4 * j]);
        const float4 vf = *reinterpret_cast<const float4*>(&W_hh[(1 * 64 + l) * 64 + 4 * j]);
        const float4 vg = *reinterpret_cast<const float4*>(&W_hh[(2 * 64 + l) * 64 + 4 * j]);
        const float4 vo = *reinterpret_cast<const float4*>(&W_hh[(3 * 64 + l) * 64 + 4 * j]);
        wi[2 * j] = packh2(vi.x, vi.y);  wi[2 * j + 1] = packh2(vi.z, vi.w);
        wf[2 * j] = packh2(vf.x, vf.y);  wf[2 * j + 1] = packh2(vf.z, vf.w);
        wg[2 * j] = packh2(vg.x, vg.y);  wg[2 * j + 1] = packh2(vg.z, vg.w);
        wo_[2 * j] = packh2(vo.x, vo.y); wo_[2 * j + 1] = packh2(vo.z, vo.w);
    }

    const float wih_i = W_ih[l],       bia_i = b_ih[l]       + b_hh[l];
    const float wih_f = W_ih[64 + l],  bia_f = b_ih[64 + l]  + b_hh[64 + l];
    const float wih_g = W_ih[128 + l], bia_g = b_ih[128 + l] + b_hh[128 + l];
    const float wih_o = W_ih[192 + l], bia_o = b_ih[192 + l] + b_hh[192 + l];
    const float wo_l  = W_out[l];
    const float bo    = b_out[0];

    float c = 0.f, hn = 0.f;
    unsigned hpk = 0;                 // packed (h[2j],h[2j+1])

    // x window 0: lane s holds x[s*B + b]
    float xwin = x[(size_t)l * BB + b];

    #pragma unroll 1
    for (int t = 0; t < TT; ++t) {
        const int s = t & 63;
        const float xv = rlanef(xwin, s);   // uniform dynamic lane index -> 1 VALU op

        float ai0 = fmaf(xv, wih_i, bia_i), ai1 = 0.f;
        float af0 = fmaf(xv, wih_f, bia_f), af1 = 0.f;
        float ag0 = fmaf(xv, wih_g, bia_g), ag1 = 0.f;
        float ao0 = fmaf(xv, wih_o, bia_o), ao1 = 0.f;
        #pragma unroll
        for (int j = 0; j < 16; ++j) {
            const unsigned hpA = (unsigned)__builtin_amdgcn_readlane((int)hpk, 4 * j);
            const unsigned hpB = (unsigned)__builtin_amdgcn_readlane((int)hpk, 4 * j + 2);
            ai0 = fdot2u(wi[2 * j],      hpA, ai0);
            af0 = fdot2u(wf[2 * j],      hpA, af0);
            ag0 = fdot2u(wg[2 * j],      hpA, ag0);
            ao0 = fdot2u(wo_[2 * j],     hpA, ao0);
            ai1 = fdot2u(wi[2 * j + 1],  hpB, ai1);
            af1 = fdot2u(wf[2 * j + 1],  hpB, af1);
            ag1 = fdot2u(wg[2 * j + 1],  hpB, ag1);
            ao1 = fdot2u(wo_[2 * j + 1], hpB, ao1);
        }
        const float iv = sigm(ai0 + ai1);
        const float fv = sigm(af0 + af1);
        const float gg = tanh_fast(ag0 + ag1);
        const float ov = sigm(ao0 + ao1);
        c  = fmaf(fv, c, iv * gg);
        hn = ov * tanh_fast(c);

        // repack h for next step's broadcast: lane pair swap via DPP quad_perm
        const float hb = __uint_as_float((unsigned)__builtin_amdgcn_mov_dpp(
            (int)__float_as_uint(hn), 0xB1, 0xF, 0xF, true));
        H2U hh; hh.p = __builtin_amdgcn_cvt_pkrtz(hn, hb);
        hpk = hh.u;

        pbuf[s][l] = hn * wo_l;       // output partial (stride-1, conflict-free)

        if (s == 63) {
            __syncthreads();          // 1-wave barrier: orders LDS (cheap)
            const float xold = xwin;  // x for this window (lane l = step t0+l)
            const int t0n = t + 1;    // next window start
            if (t0n < TT) {           // prefetch next x window (in flight over reduce)
                xwin = x[(size_t)(t0n + l) * BB + b];
            }
            // lane l reduces row l -> output for step t0+l
            float s0 = 0.f, s1 = 0.f, s2 = 0.f, s3 = 0.f;
            #pragma unroll
            for (int j2 = 0; j2 < 16; ++j2) {
                const float4 v = *reinterpret_cast<const float4*>(&pbuf[l][4 * j2]);
                s0 += v.x; s1 += v.y; s2 += v.z; s3 += v.w;
            }
            const int tt = (t & ~63) + l;
            out[(size_t)tt * BB + b] = (s0 + s1) + (s2 + s3) + bo + xold;
        }
    }
}

extern "C" void kernel_launch(void* const* d_in, const int* in_sizes, int n_in,
                              void* d_out, int out_size, void* d_ws, size_t ws_size,
                              hipStream_t stream) {
    (void)in_sizes; (void)n_in; (void)d_ws; (void)ws_size; (void)out_size;
    const float* x    = (const float*)d_in[0];
    const float* wih  = (const float*)d_in[1];
    const float* whh  = (const float*)d_in[2];
    const float* bih  = (const float*)d_in[3];
    const float* bhh  = (const float*)d_in[4];
    const float* wout = (const float*)d_in[5];
    const float* bout = (const float*)d_in[6];
    hipLaunchKernelGGL(lstm_fused, dim3(BB), dim3(64), 0, stream,
                       x, wih, whh, bih, bhh, wout, bout, (float*)d_out);
}